// Round 3
// baseline (444.064 us; speedup 1.0000x reference)
//
#include <hip/hip_runtime.h>
#include <hip/hip_bf16.h>

// VQ-VAE vector quantizer, MI355X — round 9.
// Round-8 post-mortem: halving MFMA work did NOT help (177->198us) — kernel is
// latency-bound at 21% occupancy (2 blocks/CU, capped by 43KB LDS). Round 9
// buys occupancy: z_lds (33.8KB) deleted — A_n/refine/epilogue read z straight
// from global (same values -> bit-identical results; all L2-warm). LDS ~9KB ->
// 4-5 blocks/CU (VGPR-limited). Mid-loop threshold refreshes dropped (pure
// latency; bootstrap-128 threshold is tight enough, QCAP=1024 absorbs the
// extra candidates). afrag z-loads issued first to overlap HBM first-touch
// with A_n. launch_bounds(256,4) pins VGPR<=128 so occupancy can't regress.
//
// d_out (float32): [0..16777215] z_q_st, [16777216] vq_loss, [+1..] indices.
// d_ws: [0,512K) cb_swz; [512K,+4K) c2; [528384,+16K) partials f64.

constexpr int D     = 256;
constexpr int NC    = 1024;
constexpr int NROWS = 65536;
constexpr int RPB   = 32;        // rows per block
constexpr int NBLK  = NROWS / RPB;   // 2048
constexpr int QCAP  = 1024;      // block-wide candidate queue capacity
#define MARGIN_Q 3.8e-3f         // 3e-3 screen margin + 8e-4 bf16-store slack

typedef float accv4  __attribute__((ext_vector_type(4)));
typedef short short8 __attribute__((ext_vector_type(8)));

__device__ __forceinline__ short f2bf(float x) {
    __hip_bfloat16 h = __float2bfloat16(x);   // RNE (prep kernel only)
    return *reinterpret_cast<short*>(&h);
}
// pack truncated bf16(x) into low16, bf16(y) into high16 (2 VALU ops)
__device__ __forceinline__ unsigned packtrunc(float x, float y) {
    return (__float_as_uint(x) >> 16) | (__float_as_uint(y) & 0xffff0000u);
}

// numpy pairwise sum of x[0..127]^2 — 8-chain scheme (round-2 verified).
__device__ __forceinline__ float np_pairwise_sq128(const float* __restrict__ x) {
    float r[8];
    #pragma unroll
    for (int j = 0; j < 8; ++j) r[j] = __fmul_rn(x[j], x[j]);
    #pragma unroll
    for (int i = 8; i < 128; i += 8)
        #pragma unroll
        for (int j = 0; j < 8; ++j)
            r[j] = __fadd_rn(r[j], __fmul_rn(x[i + j], x[i + j]));
    float s01 = __fadd_rn(r[0], r[1]);
    float s23 = __fadd_rn(r[2], r[3]);
    float s45 = __fadd_rn(r[4], r[5]);
    float s67 = __fadd_rn(r[6], r[7]);
    return __fadd_rn(__fadd_rn(s01, s23), __fadd_rn(s45, s67));
}

// --- prep: per-code norms (round-2 identical) -------------------------------
__global__ void c2_kernel(const float* __restrict__ cb, float* __restrict__ c2) {
    int t = blockIdx.x * blockDim.x + threadIdx.x;
    if (t < NC) {
        const float* x = cb + (size_t)t * D;
        c2[t] = __fadd_rn(np_pairwise_sq128(x), np_pairwise_sq128(x + 128));
    }
}

// --- prep: swizzle codebook into MFMA B-fragment byte image -----------------
// short8 element t = tile*512 + ks*64 + lane holds
//   cb[tile*16 + (lane&15)][ks*32 + (lane>>4)*8 + j],  j=0..7
__global__ void swz_kernel(const float* __restrict__ cb, short* __restrict__ swz) {
    int t = blockIdx.x * blockDim.x + threadIdx.x;   // 0..32767
    int lane = t & 63, ts = t >> 6;
    int ks = ts & 7, tile = ts >> 3;
    int code = tile * 16 + (lane & 15);
    int kb   = ks * 32 + (lane >> 4) * 8;
    const float* src = cb + (size_t)code * D + kb;
    union { short s[8]; short8 v; } u;
    #pragma unroll
    for (int j = 0; j < 8; ++j) u.s[j] = f2bf(src[j]);
    *((short8*)swz + t) = u.v;
}

// --- main: LDS-lean 1-pass screen + flat refine + epilogue ------------------
__global__ __launch_bounds__(256, 4) void vq_kernel(
    const float* __restrict__ z,
    const float* __restrict__ cb,
    const short* __restrict__ cb_swz,
    const float* __restrict__ c2g,
    float*       __restrict__ out_zq,
    float*       __restrict__ out_idx,
    double*      __restrict__ partials)
{
    __shared__ float c2_lds[NC];                        // 4096 B
    __shared__ float a_row[RPB];
    __shared__ __align__(16) float scratchA[RPB][4];    // A_n tree; then best64
    __shared__ int   rm_shared[RPB];                    // approx min; then winners
    __shared__ __align__(16) int queue[QCAP];           // 4096 B; then f64 scratch
    __shared__ int   qn;

    const int tid     = threadIdx.x;
    const int lane    = tid & 63;
    const int w       = tid >> 6;         // wave 0..3
    const int rowBase = blockIdx.x * RPB;

    // ---- phase 0: init small LDS ----
    #pragma unroll
    for (int j = 0; j < 4; ++j) c2_lds[tid + 256 * j] = c2g[tid + 256 * j];
    if (tid < RPB) rm_shared[tid] = 0x7f800000;   // +inf
    if (tid == 0)  qn = 0;

    // ---- phase 1: A-fragments from GLOBAL z (truncated bf16) — issued first
    // so the HBM first-touch latency overlaps the A_n chains below.
    // lane L, row-tile rt, k-slice ks: rows rt*16+(L&15), dims ks*32+(L>>4)*8..+7
    short8 afrag[2][8];
    #pragma unroll
    for (int rt = 0; rt < 2; ++rt)
        #pragma unroll
        for (int ks = 0; ks < 8; ++ks) {
            const float* src = z + (size_t)(rowBase + rt * 16 + (lane & 15)) * D
                                 + ks * 32 + (lane >> 4) * 8;
            float4 v0 = *(const float4*)(src);
            float4 v1 = *(const float4*)(src + 4);
            union { unsigned u[4]; short8 v; } pk;
            pk.u[0] = packtrunc(v0.x, v0.y);
            pk.u[1] = packtrunc(v0.z, v0.w);
            pk.u[2] = packtrunc(v1.x, v1.y);
            pk.u[3] = packtrunc(v1.z, v1.w);
            afrag[rt][ks] = pk.v;
        }

    // ---- phase 2: A_n (numpy pairwise, round-2-exact tree), 4 threads/row,
    // sourced from global (L1/L2-hit after phase 1; identical values) ----
    if (tid < RPB * 4) {
        int row = tid >> 2, q = tid & 3;
        int h = (q >> 1) * 128, p = (q & 1) * 4;
        const float* x = z + (size_t)(rowBase + row) * D;
        float r0 = __fmul_rn(x[h+p+0], x[h+p+0]);
        float r1 = __fmul_rn(x[h+p+1], x[h+p+1]);
        float r2 = __fmul_rn(x[h+p+2], x[h+p+2]);
        float r3 = __fmul_rn(x[h+p+3], x[h+p+3]);
        #pragma unroll
        for (int i = 8; i < 128; i += 8) {
            r0 = __fadd_rn(r0, __fmul_rn(x[h+i+p+0], x[h+i+p+0]));
            r1 = __fadd_rn(r1, __fmul_rn(x[h+i+p+1], x[h+i+p+1]));
            r2 = __fadd_rn(r2, __fmul_rn(x[h+i+p+2], x[h+i+p+2]));
            r3 = __fadd_rn(r3, __fmul_rn(x[h+i+p+3], x[h+i+p+3]));
        }
        scratchA[row][q] = __fadd_rn(__fadd_rn(r0, r1), __fadd_rn(r2, r3));
    }
    __syncthreads();
    if (tid < RPB) {
        float half0 = __fadd_rn(scratchA[tid][0], scratchA[tid][1]);
        float half1 = __fadd_rn(scratchA[tid][2], scratchA[tid][3]);
        a_row[tid]  = __fadd_rn(half0, half1);
    }
    __syncthreads();

    float a_reg[2][4];
    #pragma unroll
    for (int rt = 0; rt < 2; ++rt)
        #pragma unroll
        for (int i = 0; i < 4; ++i)
            a_reg[rt][i] = a_row[rt * 16 + (lane >> 4) * 4 + i];

    // ---- phase 3: SINGLE-pass MFMA screen with online enqueue ----
    // key(row,code) = a - m,  m = 2*(z.c)_bf16 - ||c||^2.
    // rm_shared only decreases => the bootstrap threshold is conservative.
    float runmin[2][4];
    #pragma unroll
    for (int rt = 0; rt < 2; ++rt)
        #pragma unroll
        for (int i = 0; i < 4; ++i) runmin[rt][i] = 3.4e38f;

    const short8* bbase = (const short8*)cb_swz + lane;
    short8 bcur[8];
    #pragma unroll
    for (int ks = 0; ks < 8; ++ks) bcur[ks] = bbase[(size_t)w * 512 + ks * 64];

    // -- bootstrap: steps 0..1, keys cached in 8 VGPRs --
    unsigned kpk[2][2][2];
    #pragma unroll
    for (int t = 0; t < 2; ++t) {
        const int tile = w + 4 * t;
        short8 bnxt[8];
        #pragma unroll
        for (int ks = 0; ks < 8; ++ks)
            bnxt[ks] = bbase[(size_t)(tile + 4) * 512 + ks * 64];
        accv4 acc[2];
        #pragma unroll
        for (int rt = 0; rt < 2; ++rt) acc[rt] = (accv4){0.f, 0.f, 0.f, 0.f};
        #pragma unroll
        for (int ks = 0; ks < 8; ++ks) {
            #pragma unroll
            for (int rt = 0; rt < 2; ++rt)
                acc[rt] = __builtin_amdgcn_mfma_f32_16x16x32_bf16(
                    afrag[rt][ks], bcur[ks], acc[rt], 0, 0, 0);
        }
        const float c2v = c2_lds[tile * 16 + (lane & 15)];
        #pragma unroll
        for (int rt = 0; rt < 2; ++rt) {
            float m0 = fmaf(2.0f, acc[rt][0], -c2v);
            float m1 = fmaf(2.0f, acc[rt][1], -c2v);
            float m2 = fmaf(2.0f, acc[rt][2], -c2v);
            float m3 = fmaf(2.0f, acc[rt][3], -c2v);
            kpk[t][rt][0] = packtrunc(m0, m1);
            kpk[t][rt][1] = packtrunc(m2, m3);
            runmin[rt][0] = fminf(runmin[rt][0], a_reg[rt][0] - m0);
            runmin[rt][1] = fminf(runmin[rt][1], a_reg[rt][1] - m1);
            runmin[rt][2] = fminf(runmin[rt][2], a_reg[rt][2] - m2);
            runmin[rt][3] = fminf(runmin[rt][3], a_reg[rt][3] - m3);
        }
        #pragma unroll
        for (int ks = 0; ks < 8; ++ks) bcur[ks] = bnxt[ks];
    }

    // publish bootstrap mins (all waves), one barrier for the threshold
    #pragma unroll
    for (int rt = 0; rt < 2; ++rt)
        #pragma unroll
        for (int i = 0; i < 4; ++i) {
            float m = runmin[rt][i];
            m = fminf(m, __shfl_xor(m, 1));
            m = fminf(m, __shfl_xor(m, 2));
            m = fminf(m, __shfl_xor(m, 4));
            m = fminf(m, __shfl_xor(m, 8));
            if ((lane & 15) == 0) {
                int row = rt * 16 + (lane >> 4) * 4 + i;
                atomicMin(&rm_shared[row], __float_as_int(m));
            }
        }
    __syncthreads();

    float mthr[2][4];      // enqueue iff m >= mthr  (<=> key <= min + margin)
    #pragma unroll
    for (int rt = 0; rt < 2; ++rt)
        #pragma unroll
        for (int i = 0; i < 4; ++i) {
            int row = rt * 16 + (lane >> 4) * 4 + i;
            mthr[rt][i] = a_reg[rt][i]
                        - (__int_as_float(rm_shared[row]) + MARGIN_Q);
        }

    // scan the 2-step bootstrap cache
    #pragma unroll
    for (int t = 0; t < 2; ++t) {
        const int code = (w + 4 * t) * 16 + (lane & 15);
        #pragma unroll
        for (int rt = 0; rt < 2; ++rt)
            #pragma unroll
            for (int pr = 0; pr < 2; ++pr) {
                unsigned pk = kpk[t][rt][pr];
                float mlo = __uint_as_float(pk << 16);
                float mhi = __uint_as_float(pk & 0xffff0000u);
                if (mlo >= mthr[rt][2 * pr]) {
                    int row  = rt * 16 + (lane >> 4) * 4 + 2 * pr;
                    int slot = atomicAdd(&qn, 1);
                    if (slot < QCAP) queue[slot] = (row << 10) | code;
                }
                if (mhi >= mthr[rt][2 * pr + 1]) {
                    int row  = rt * 16 + (lane >> 4) * 4 + 2 * pr + 1;
                    int slot = atomicAdd(&qn, 1);
                    if (slot < QCAP) queue[slot] = (row << 10) | code;
                }
            }
    }

    // -- online: steps 2..15, enqueue as we go (no mid-loop refresh) --
    for (int t = 2; t < 16; ++t) {
        const int tile = w + 4 * t;
        short8 bnxt[8];
        if (t < 15) {
            #pragma unroll
            for (int ks = 0; ks < 8; ++ks)
                bnxt[ks] = bbase[(size_t)(tile + 4) * 512 + ks * 64];
        }
        accv4 acc[2];
        #pragma unroll
        for (int rt = 0; rt < 2; ++rt) acc[rt] = (accv4){0.f, 0.f, 0.f, 0.f};
        #pragma unroll
        for (int ks = 0; ks < 8; ++ks) {
            #pragma unroll
            for (int rt = 0; rt < 2; ++rt)
                acc[rt] = __builtin_amdgcn_mfma_f32_16x16x32_bf16(
                    afrag[rt][ks], bcur[ks], acc[rt], 0, 0, 0);
        }
        const float c2v  = c2_lds[tile * 16 + (lane & 15)];
        const int   code = tile * 16 + (lane & 15);
        #pragma unroll
        for (int rt = 0; rt < 2; ++rt) {
            #pragma unroll
            for (int i = 0; i < 4; ++i) {
                float m = fmaf(2.0f, acc[rt][i], -c2v);
                runmin[rt][i] = fminf(runmin[rt][i], a_reg[rt][i] - m);
                if (m >= mthr[rt][i]) {
                    int row  = rt * 16 + (lane >> 4) * 4 + i;
                    int slot = atomicAdd(&qn, 1);
                    if (slot < QCAP) queue[slot] = (row << 10) | code;
                }
            }
        }
        if (t < 15) {
            #pragma unroll
            for (int ks = 0; ks < 8; ++ks) bcur[ks] = bnxt[ks];
        }
    }

    // ---- phase 4: exact refinement (z from global; bit-identical keys) ----
    unsigned long long* best64 = (unsigned long long*)&scratchA[0][0];
    if (tid < RPB) best64[tid] = ~0ull;
    __syncthreads();
    int total = qn;
    if (total <= QCAP) {
        for (int t = tid; t < total; t += 256) {
            int e = queue[t];
            int row = e >> 10, code = e & 1023;
            const float4* cp = (const float4*)(cb + (size_t)code * D);
            const float*  zr = z + (size_t)(rowBase + row) * D;
            float acc = 0.0f;
            #pragma unroll 8
            for (int d4 = 0; d4 < 64; ++d4) {
                float4 cv = cp[d4];
                acc = fmaf(zr[d4 * 4 + 0], cv.x, acc);
                acc = fmaf(zr[d4 * 4 + 1], cv.y, acc);
                acc = fmaf(zr[d4 * 4 + 2], cv.z, acc);
                acc = fmaf(zr[d4 * 4 + 3], cv.w, acc);
            }
            float key = __fsub_rn(__fadd_rn(a_row[row], c2_lds[code]), 2.0f * acc);
            unsigned long long pk =
                ((unsigned long long)__float_as_uint(key) << 32) | (unsigned)code;
            atomicMin(&best64[row], pk);
        }
    } else {
        for (int r = 0; r < RPB; ++r) {
            for (int c = tid; c < NC; c += 256) {
                const float4* cp = (const float4*)(cb + (size_t)c * D);
                const float*  zr = z + (size_t)(rowBase + r) * D;
                float acc = 0.0f;
                #pragma unroll 8
                for (int d4 = 0; d4 < 64; ++d4) {
                    float4 cv = cp[d4];
                    acc = fmaf(zr[d4 * 4 + 0], cv.x, acc);
                    acc = fmaf(zr[d4 * 4 + 1], cv.y, acc);
                    acc = fmaf(zr[d4 * 4 + 2], cv.z, acc);
                    acc = fmaf(zr[d4 * 4 + 3], cv.w, acc);
                }
                float key = __fsub_rn(__fadd_rn(a_row[r], c2_lds[c]), 2.0f * acc);
                unsigned long long pk =
                    ((unsigned long long)__float_as_uint(key) << 32) | (unsigned)c;
                atomicMin(&best64[r], pk);
            }
        }
    }
    __syncthreads();

    // ---- phase 5: winners ----
    int* winner = rm_shared;   // reuse
    if (tid < RPB) {
        unsigned long long b = best64[tid];
        int wdx = (b == ~0ull) ? 0 : (int)(b & 0xffffffffu);
        winner[tid] = wdx;
        out_idx[rowBase + tid] = (float)wdx;
    }
    __syncthreads();

    // ---- phase 6: vectorized epilogue (z from global, fully coalesced) ----
    double lacc = 0.0;
    #pragma unroll
    for (int j = 0; j < 8; ++j) {
        int idx = tid + 256 * j;      // 0..2047
        int row = idx >> 6;           // wave-uniform
        int q4  = idx & 63;
        int wd  = winner[row];
        float4 cv = *(const float4*)(cb + (size_t)wd * D + q4 * 4);
        float4 zv = *(const float4*)(z + (size_t)(rowBase + row) * D + q4 * 4);
        float4 o;
        o.x = __fadd_rn(zv.x, __fsub_rn(cv.x, zv.x));
        o.y = __fadd_rn(zv.y, __fsub_rn(cv.y, zv.y));
        o.z = __fadd_rn(zv.z, __fsub_rn(cv.z, zv.z));
        o.w = __fadd_rn(zv.w, __fsub_rn(cv.w, zv.w));
        *(float4*)(out_zq + (size_t)(rowBase + row) * D + q4 * 4) = o;
        double d0 = (double)zv.x - (double)cv.x;
        double d1 = (double)zv.y - (double)cv.y;
        double d2 = (double)zv.z - (double)cv.z;
        double d3 = (double)zv.w - (double)cv.w;
        lacc += d0 * d0 + d1 * d1 + d2 * d2 + d3 * d3;
    }
    __syncthreads();
    double* dred = (double*)&queue[0];   // 256 doubles = 2048 B, fits in queue
    dred[tid] = lacc;
    __syncthreads();
    for (int s = 128; s > 0; s >>= 1) {
        if (tid < s) dred[tid] += dred[tid + s];
        __syncthreads();
    }
    if (tid == 0) partials[blockIdx.x] = dred[0];
}

// --- final loss reduction ---------------------------------------------------
__global__ void loss_kernel(const double* __restrict__ partials,
                            float* __restrict__ out_loss)
{
    __shared__ double sm[256];
    int tid = threadIdx.x;
    double s = 0.0;
    for (int i = tid; i < NBLK; i += 256) s += partials[i];
    sm[tid] = s;
    __syncthreads();
    for (int k = 128; k > 0; k >>= 1) {
        if (tid < k) sm[tid] += sm[tid + k];
        __syncthreads();
    }
    if (tid == 0)
        out_loss[0] = (float)(1.25 * sm[0] / (double)((size_t)NROWS * D));
}

extern "C" void kernel_launch(void* const* d_in, const int* in_sizes, int n_in,
                              void* d_out, int out_size, void* d_ws, size_t ws_size,
                              hipStream_t stream)
{
    const float* z  = (const float*)d_in[0];   // [65536, 256]
    const float* cb = (const float*)d_in[1];   // [1024, 256]

    float* out      = (float*)d_out;
    float* out_zq   = out;
    float* out_loss = out + (size_t)NROWS * D;
    float* out_idx  = out_loss + 1;

    char*   ws       = (char*)d_ws;
    short*  cb_swz   = (short*)ws;                       // 512 KB
    float*  c2       = (float*)(ws + 524288);            // 4 KB
    double* partials = (double*)(ws + 528384);           // 16 KB

    swz_kernel<<<128, 256, 0, stream>>>(cb, cb_swz);
    c2_kernel<<<4, 256, 0, stream>>>(cb, c2);
    vq_kernel<<<NBLK, 256, 0, stream>>>(z, cb, cb_swz, c2,
                                        out_zq, out_idx, partials);
    loss_kernel<<<1, 256, 0, stream>>>(partials, out_loss);
}

// Round 4
// 415.992 us; speedup vs baseline: 1.0675x; 1.0675x over previous
//
#include <hip/hip_runtime.h>
#include <hip/hip_bf16.h>

// VQ-VAE vector quantizer, MI355X — round 10.
// Rounds 6-9 post-mortem: latency/structure-bound (all pipes <27%). Round 10
// restructures: (a) screen kernel GEMM-ified — 128 rows/block, B-tile (16
// codes, 8KB) staged to LDS via global_load_lds double-buffer, shared by 4
// waves (each holds afrag for 32 rows = 64 VGPR, r6-verified size). B L2
// traffic 1GB -> 256MB; inner loop fed by LDS not L2-latency. grid 512 = 2
// resident blocks/CU -> wall ~ one block duration. (b) epilogue split into a
// separate streaming kernel (gather + z_q + loss partials, grid 2048) that
// reproduces r6's loss double-sum tree bit-for-bit and profiles separately.
// Screen numerics (bootstrap-128 threshold, online enqueue, exact fp32
// refine + overflow fallback) identical to verified r8/r9 scheme.
//
// d_out (float32): [0..16777215] z_q_st, [16777216] vq_loss, [+1..] indices.
// d_ws: [0,512K) cb_swz; [512K,+4K) c2; [528384,+16K) partials f64.

constexpr int D      = 256;
constexpr int NC     = 1024;
constexpr int NROWS  = 65536;
constexpr int RPB_S  = 128;              // rows per screen block
constexpr int NBLK_S = NROWS / RPB_S;    // 512
constexpr int RPB_O  = 32;               // rows per output block
constexpr int NBLK_O = NROWS / RPB_O;    // 2048
constexpr int QCAP   = 4096;             // candidate queue capacity (32/row)
#define MARGIN_Q 3.8e-3f

typedef float accv4  __attribute__((ext_vector_type(4)));
typedef short short8 __attribute__((ext_vector_type(8)));

__device__ __forceinline__ short f2bf(float x) {
    __hip_bfloat16 h = __float2bfloat16(x);   // RNE (prep kernel only)
    return *reinterpret_cast<short*>(&h);
}
// pack truncated bf16(x) into low16, bf16(y) into high16
__device__ __forceinline__ unsigned packtrunc(float x, float y) {
    return (__float_as_uint(x) >> 16) | (__float_as_uint(y) & 0xffff0000u);
}
// async global -> LDS, 16 bytes per lane
__device__ __forceinline__ void gld16(const void* g, void* l) {
    __builtin_amdgcn_global_load_lds(
        (const __attribute__((address_space(1))) unsigned*)g,
        (__attribute__((address_space(3))) unsigned*)l, 16, 0, 0);
}

// numpy pairwise sum of x[0..127]^2 — 8-chain scheme (round-2 verified).
__device__ __forceinline__ float np_pairwise_sq128(const float* __restrict__ x) {
    float r[8];
    #pragma unroll
    for (int j = 0; j < 8; ++j) r[j] = __fmul_rn(x[j], x[j]);
    #pragma unroll
    for (int i = 8; i < 128; i += 8)
        #pragma unroll
        for (int j = 0; j < 8; ++j)
            r[j] = __fadd_rn(r[j], __fmul_rn(x[i + j], x[i + j]));
    float s01 = __fadd_rn(r[0], r[1]);
    float s23 = __fadd_rn(r[2], r[3]);
    float s45 = __fadd_rn(r[4], r[5]);
    float s67 = __fadd_rn(r[6], r[7]);
    return __fadd_rn(__fadd_rn(s01, s23), __fadd_rn(s45, s67));
}

// --- prep: per-code norms (round-2 identical) -------------------------------
__global__ void c2_kernel(const float* __restrict__ cb, float* __restrict__ c2) {
    int t = blockIdx.x * blockDim.x + threadIdx.x;
    if (t < NC) {
        const float* x = cb + (size_t)t * D;
        c2[t] = __fadd_rn(np_pairwise_sq128(x), np_pairwise_sq128(x + 128));
    }
}

// --- prep: swizzle codebook into MFMA B-fragment byte image -----------------
// short8 element t = tile*512 + ks*64 + lane holds
//   cb[tile*16 + (lane&15)][ks*32 + (lane>>4)*8 + j],  j=0..7
__global__ void swz_kernel(const float* __restrict__ cb, short* __restrict__ swz) {
    int t = blockIdx.x * blockDim.x + threadIdx.x;   // 0..32767
    int lane = t & 63, ts = t >> 6;
    int ks = ts & 7, tile = ts >> 3;
    int code = tile * 16 + (lane & 15);
    int kb   = ks * 32 + (lane >> 4) * 8;
    const float* src = cb + (size_t)code * D + kb;
    union { short s[8]; short8 v; } u;
    #pragma unroll
    for (int j = 0; j < 8; ++j) u.s[j] = f2bf(src[j]);
    *((short8*)swz + t) = u.v;
}

// --- screen: 128-row GEMM-style argmin, B via LDS double-buffer -------------
__global__ __launch_bounds__(256, 2) void screen_kernel(
    const float* __restrict__ z,
    const float* __restrict__ cb,
    const short* __restrict__ cb_swz,
    const float* __restrict__ c2g,
    float*       __restrict__ out_idx)
{
    __shared__ __align__(16) short bB[2][4096];        // 2 x 8 KB B-tile dbuf
    __shared__ float c2_lds[NC];                        // 4 KB
    __shared__ float a_row[RPB_S];
    __shared__ __align__(16) float scratchA[RPB_S][4]; // A_n tree; then best64
    __shared__ int   rm_shared[RPB_S];
    __shared__ __align__(16) int queue[QCAP];          // 16 KB
    __shared__ int   qn;

    const int tid     = threadIdx.x;
    const int lane    = tid & 63;
    const int w       = tid >> 6;         // wave 0..3
    const int rowBase = blockIdx.x * RPB_S;

    // ---- init small LDS ----
    #pragma unroll
    for (int j = 0; j < 4; ++j) c2_lds[tid + 256 * j] = c2g[tid + 256 * j];
    if (tid < RPB_S) rm_shared[tid] = 0x7f800000;   // +inf
    if (tid == 0)    qn = 0;

    // ---- A-fragments from global z (truncated bf16; r8/r9-verified) ----
    // wave w owns rows [w*32, w*32+32): rt*16 + (lane&15); dims ks*32+(lane>>4)*8
    short8 afrag[2][8];
    #pragma unroll
    for (int rt = 0; rt < 2; ++rt)
        #pragma unroll
        for (int ks = 0; ks < 8; ++ks) {
            const float* src = z
                + (size_t)(rowBase + w * 32 + rt * 16 + (lane & 15)) * D
                + ks * 32 + (lane >> 4) * 8;
            float4 v0 = *(const float4*)(src);
            float4 v1 = *(const float4*)(src + 4);
            union { unsigned u[4]; short8 v; } pk;
            pk.u[0] = packtrunc(v0.x, v0.y);
            pk.u[1] = packtrunc(v0.z, v0.w);
            pk.u[2] = packtrunc(v1.x, v1.y);
            pk.u[3] = packtrunc(v1.z, v1.w);
            afrag[rt][ks] = pk.v;
        }

    // ---- A_n (numpy pairwise, round-2-exact tree), 4 threads/row, 2 halves --
    #pragma unroll
    for (int hf = 0; hf < 2; ++hf) {
        int row = hf * 64 + (tid >> 2), q = tid & 3;
        int h = (q >> 1) * 128, p = (q & 1) * 4;
        const float* x = z + (size_t)(rowBase + row) * D;
        float r0 = __fmul_rn(x[h+p+0], x[h+p+0]);
        float r1 = __fmul_rn(x[h+p+1], x[h+p+1]);
        float r2 = __fmul_rn(x[h+p+2], x[h+p+2]);
        float r3 = __fmul_rn(x[h+p+3], x[h+p+3]);
        #pragma unroll
        for (int i = 8; i < 128; i += 8) {
            r0 = __fadd_rn(r0, __fmul_rn(x[h+i+p+0], x[h+i+p+0]));
            r1 = __fadd_rn(r1, __fmul_rn(x[h+i+p+1], x[h+i+p+1]));
            r2 = __fadd_rn(r2, __fmul_rn(x[h+i+p+2], x[h+i+p+2]));
            r3 = __fadd_rn(r3, __fmul_rn(x[h+i+p+3], x[h+i+p+3]));
        }
        scratchA[row][q] = __fadd_rn(__fadd_rn(r0, r1), __fadd_rn(r2, r3));
    }
    __syncthreads();
    if (tid < RPB_S) {
        float half0 = __fadd_rn(scratchA[tid][0], scratchA[tid][1]);
        float half1 = __fadd_rn(scratchA[tid][2], scratchA[tid][3]);
        a_row[tid]  = __fadd_rn(half0, half1);
    }
    __syncthreads();

    float a_reg[2][4];
    #pragma unroll
    for (int rt = 0; rt < 2; ++rt)
        #pragma unroll
        for (int i = 0; i < 4; ++i)
            a_reg[rt][i] = a_row[w * 32 + rt * 16 + (lane >> 4) * 4 + i];

    // ---- B-tile staging helper: tile = 16 codes = 8 KB image ----
    auto stage = [&](int tile, int buf) {
        const char* gs = (const char*)cb_swz + (size_t)tile * 8192 + tid * 16;
        char* ld = (char*)&bB[buf][0] + tid * 16;
        gld16(gs, ld);
        gld16(gs + 4096, ld + 4096);
    };

    // prologue: tile 0 -> buf 0 (barrier drains vmcnt)
    stage(0, 0);
    __syncthreads();

    float runmin[2][4];
    #pragma unroll
    for (int rt = 0; rt < 2; ++rt)
        #pragma unroll
        for (int i = 0; i < 4; ++i) runmin[rt][i] = 3.4e38f;

    // ---- bootstrap: tiles 0..7 (codes 0..127), keys cached in 32 VGPRs ----
    unsigned kpk[8][2][2];
    #pragma unroll
    for (int t = 0; t < 8; ++t) {
        stage(t + 1, (t + 1) & 1);
        const short* bp = &bB[t & 1][0];
        short8 bf[8];
        #pragma unroll
        for (int ks = 0; ks < 8; ++ks)
            bf[ks] = *(const short8*)(bp + (ks * 64 + lane) * 8);
        accv4 acc[2];
        #pragma unroll
        for (int rt = 0; rt < 2; ++rt) acc[rt] = (accv4){0.f, 0.f, 0.f, 0.f};
        #pragma unroll
        for (int ks = 0; ks < 8; ++ks) {
            #pragma unroll
            for (int rt = 0; rt < 2; ++rt)
                acc[rt] = __builtin_amdgcn_mfma_f32_16x16x32_bf16(
                    afrag[rt][ks], bf[ks], acc[rt], 0, 0, 0);
        }
        const float c2v = c2_lds[t * 16 + (lane & 15)];
        #pragma unroll
        for (int rt = 0; rt < 2; ++rt) {
            float m0 = fmaf(2.0f, acc[rt][0], -c2v);
            float m1 = fmaf(2.0f, acc[rt][1], -c2v);
            float m2 = fmaf(2.0f, acc[rt][2], -c2v);
            float m3 = fmaf(2.0f, acc[rt][3], -c2v);
            kpk[t][rt][0] = packtrunc(m0, m1);
            kpk[t][rt][1] = packtrunc(m2, m3);
            runmin[rt][0] = fminf(runmin[rt][0], a_reg[rt][0] - m0);
            runmin[rt][1] = fminf(runmin[rt][1], a_reg[rt][1] - m1);
            runmin[rt][2] = fminf(runmin[rt][2], a_reg[rt][2] - m2);
            runmin[rt][3] = fminf(runmin[rt][3], a_reg[rt][3] - m3);
        }
        __syncthreads();
    }

    // publish bootstrap mins, one barrier, compute enqueue threshold
    #pragma unroll
    for (int rt = 0; rt < 2; ++rt)
        #pragma unroll
        for (int i = 0; i < 4; ++i) {
            float m = runmin[rt][i];
            m = fminf(m, __shfl_xor(m, 1));
            m = fminf(m, __shfl_xor(m, 2));
            m = fminf(m, __shfl_xor(m, 4));
            m = fminf(m, __shfl_xor(m, 8));
            if ((lane & 15) == 0) {
                int row = w * 32 + rt * 16 + (lane >> 4) * 4 + i;
                atomicMin(&rm_shared[row], __float_as_int(m));
            }
        }
    __syncthreads();

    float mthr[2][4];      // enqueue iff m >= mthr  (<=> key <= min + margin)
    #pragma unroll
    for (int rt = 0; rt < 2; ++rt)
        #pragma unroll
        for (int i = 0; i < 4; ++i) {
            int row = w * 32 + rt * 16 + (lane >> 4) * 4 + i;
            mthr[rt][i] = a_reg[rt][i]
                        - (__int_as_float(rm_shared[row]) + MARGIN_Q);
        }

    // scan the bootstrap cache
    #pragma unroll
    for (int t = 0; t < 8; ++t) {
        const int code = t * 16 + (lane & 15);
        #pragma unroll
        for (int rt = 0; rt < 2; ++rt)
            #pragma unroll
            for (int pr = 0; pr < 2; ++pr) {
                unsigned pk = kpk[t][rt][pr];
                float mlo = __uint_as_float(pk << 16);
                float mhi = __uint_as_float(pk & 0xffff0000u);
                if (mlo >= mthr[rt][2 * pr]) {
                    int row  = w * 32 + rt * 16 + (lane >> 4) * 4 + 2 * pr;
                    int slot = atomicAdd(&qn, 1);
                    if (slot < QCAP) queue[slot] = (row << 10) | code;
                }
                if (mhi >= mthr[rt][2 * pr + 1]) {
                    int row  = w * 32 + rt * 16 + (lane >> 4) * 4 + 2 * pr + 1;
                    int slot = atomicAdd(&qn, 1);
                    if (slot < QCAP) queue[slot] = (row << 10) | code;
                }
            }
    }

    // ---- online: tiles 8..63, enqueue as we go ----
    for (int t = 8; t < 64; ++t) {
        if (t + 1 < 64) stage(t + 1, (t + 1) & 1);
        const short* bp = &bB[t & 1][0];
        short8 bf[8];
        #pragma unroll
        for (int ks = 0; ks < 8; ++ks)
            bf[ks] = *(const short8*)(bp + (ks * 64 + lane) * 8);
        accv4 acc[2];
        #pragma unroll
        for (int rt = 0; rt < 2; ++rt) acc[rt] = (accv4){0.f, 0.f, 0.f, 0.f};
        #pragma unroll
        for (int ks = 0; ks < 8; ++ks) {
            #pragma unroll
            for (int rt = 0; rt < 2; ++rt)
                acc[rt] = __builtin_amdgcn_mfma_f32_16x16x32_bf16(
                    afrag[rt][ks], bf[ks], acc[rt], 0, 0, 0);
        }
        const float c2v  = c2_lds[t * 16 + (lane & 15)];
        const int   code = t * 16 + (lane & 15);
        #pragma unroll
        for (int rt = 0; rt < 2; ++rt) {
            #pragma unroll
            for (int i = 0; i < 4; ++i) {
                float m = fmaf(2.0f, acc[rt][i], -c2v);
                if (m >= mthr[rt][i]) {
                    int row  = w * 32 + rt * 16 + (lane >> 4) * 4 + i;
                    int slot = atomicAdd(&qn, 1);
                    if (slot < QCAP) queue[slot] = (row << 10) | code;
                }
            }
        }
        __syncthreads();
    }

    // ---- exact refinement (z from global; bit-identical round-2 keys) ----
    unsigned long long* best64 = (unsigned long long*)&scratchA[0][0];
    if (tid < RPB_S) best64[tid] = ~0ull;
    __syncthreads();
    int total = qn;
    if (total <= QCAP) {
        for (int t = tid; t < total; t += 256) {
            int e = queue[t];
            int row = e >> 10, code = e & 1023;
            const float4* cp = (const float4*)(cb + (size_t)code * D);
            const float*  zr = z + (size_t)(rowBase + row) * D;
            float acc = 0.0f;
            #pragma unroll 8
            for (int d4 = 0; d4 < 64; ++d4) {
                float4 cv = cp[d4];
                acc = fmaf(zr[d4 * 4 + 0], cv.x, acc);
                acc = fmaf(zr[d4 * 4 + 1], cv.y, acc);
                acc = fmaf(zr[d4 * 4 + 2], cv.z, acc);
                acc = fmaf(zr[d4 * 4 + 3], cv.w, acc);
            }
            float key = __fsub_rn(__fadd_rn(a_row[row], c2_lds[code]), 2.0f * acc);
            unsigned long long pk =
                ((unsigned long long)__float_as_uint(key) << 32) | (unsigned)code;
            atomicMin(&best64[row], pk);
        }
    } else {
        for (int r = 0; r < RPB_S; ++r) {
            for (int c = tid; c < NC; c += 256) {
                const float4* cp = (const float4*)(cb + (size_t)c * D);
                const float*  zr = z + (size_t)(rowBase + r) * D;
                float acc = 0.0f;
                #pragma unroll 8
                for (int d4 = 0; d4 < 64; ++d4) {
                    float4 cv = cp[d4];
                    acc = fmaf(zr[d4 * 4 + 0], cv.x, acc);
                    acc = fmaf(zr[d4 * 4 + 1], cv.y, acc);
                    acc = fmaf(zr[d4 * 4 + 2], cv.z, acc);
                    acc = fmaf(zr[d4 * 4 + 3], cv.w, acc);
                }
                float key = __fsub_rn(__fadd_rn(a_row[r], c2_lds[c]), 2.0f * acc);
                unsigned long long pk =
                    ((unsigned long long)__float_as_uint(key) << 32) | (unsigned)c;
                atomicMin(&best64[r], pk);
            }
        }
    }
    __syncthreads();

    if (tid < RPB_S) {
        unsigned long long b = best64[tid];
        int wdx = (b == ~0ull) ? 0 : (int)(b & 0xffffffffu);
        out_idx[rowBase + tid] = (float)wdx;
    }
}

// --- output: gather + z_q_st + loss partials (streaming; r6 loss tree) ------
__global__ void out_kernel(
    const float* __restrict__ z,
    const float* __restrict__ cb,
    const float* __restrict__ out_idx,
    float*       __restrict__ out_zq,
    double*      __restrict__ partials)
{
    __shared__ int    winner[RPB_O];
    __shared__ double dred[256];
    const int tid     = threadIdx.x;
    const int rowBase = blockIdx.x * RPB_O;

    if (tid < RPB_O) winner[tid] = (int)out_idx[rowBase + tid];
    __syncthreads();

    double lacc = 0.0;
    #pragma unroll
    for (int j = 0; j < 8; ++j) {
        int idx = tid + 256 * j;      // 0..2047
        int row = idx >> 6;           // wave-uniform
        int q4  = idx & 63;
        int wd  = winner[row];
        float4 cv = *(const float4*)(cb + (size_t)wd * D + q4 * 4);
        float4 zv = *(const float4*)(z + (size_t)(rowBase + row) * D + q4 * 4);
        float4 o;
        o.x = __fadd_rn(zv.x, __fsub_rn(cv.x, zv.x));
        o.y = __fadd_rn(zv.y, __fsub_rn(cv.y, zv.y));
        o.z = __fadd_rn(zv.z, __fsub_rn(cv.z, zv.z));
        o.w = __fadd_rn(zv.w, __fsub_rn(cv.w, zv.w));
        *(float4*)(out_zq + (size_t)(rowBase + row) * D + q4 * 4) = o;
        double d0 = (double)zv.x - (double)cv.x;
        double d1 = (double)zv.y - (double)cv.y;
        double d2 = (double)zv.z - (double)cv.z;
        double d3 = (double)zv.w - (double)cv.w;
        lacc += d0 * d0 + d1 * d1 + d2 * d2 + d3 * d3;
    }
    dred[tid] = lacc;
    __syncthreads();
    for (int s = 128; s > 0; s >>= 1) {
        if (tid < s) dred[tid] += dred[tid + s];
        __syncthreads();
    }
    if (tid == 0) partials[blockIdx.x] = dred[0];
}

// --- final loss reduction ---------------------------------------------------
__global__ void loss_kernel(const double* __restrict__ partials,
                            float* __restrict__ out_loss)
{
    __shared__ double sm[256];
    int tid = threadIdx.x;
    double s = 0.0;
    for (int i = tid; i < NBLK_O; i += 256) s += partials[i];
    sm[tid] = s;
    __syncthreads();
    for (int k = 128; k > 0; k >>= 1) {
        if (tid < k) sm[tid] += sm[tid + k];
        __syncthreads();
    }
    if (tid == 0)
        out_loss[0] = (float)(1.25 * sm[0] / (double)((size_t)NROWS * D));
}

extern "C" void kernel_launch(void* const* d_in, const int* in_sizes, int n_in,
                              void* d_out, int out_size, void* d_ws, size_t ws_size,
                              hipStream_t stream)
{
    const float* z  = (const float*)d_in[0];   // [65536, 256]
    const float* cb = (const float*)d_in[1];   // [1024, 256]

    float* out      = (float*)d_out;
    float* out_zq   = out;
    float* out_loss = out + (size_t)NROWS * D;
    float* out_idx  = out_loss + 1;

    char*   ws       = (char*)d_ws;
    short*  cb_swz   = (short*)ws;                       // 512 KB
    float*  c2       = (float*)(ws + 524288);            // 4 KB
    double* partials = (double*)(ws + 528384);           // 16 KB

    swz_kernel<<<128, 256, 0, stream>>>(cb, cb_swz);
    c2_kernel<<<4, 256, 0, stream>>>(cb, c2);
    screen_kernel<<<NBLK_S, 256, 0, stream>>>(z, cb, cb_swz, c2, out_idx);
    out_kernel<<<NBLK_O, 256, 0, stream>>>(z, cb, out_idx, out_zq, partials);
    loss_kernel<<<1, 256, 0, stream>>>(partials, out_loss);
}